// Round 3
// baseline (1361.686 us; speedup 1.0000x reference)
//
#include <hip/hip_runtime.h>
#include <hip/hip_bf16.h>
#include <stdint.h>

// Problem constants
#define B_   32
#define T_   2048
#define W_   1024
#define LIST_CAP 65536

typedef __bf16 bf16_t;
typedef __bf16 bf16x8 __attribute__((ext_vector_type(8)));
typedef float  f32x4  __attribute__((ext_vector_type(4)));

// ---------------- workspace layout (bytes) ----------------
#define WS_XT      0ull
#define WS_XT_SZ   (134217728ull)                 // 32*1024*2048*2
#define WS_MU      (WS_XT + WS_XT_SZ)             // float[32*1024]
#define WS_SIG     (WS_MU  + 131072ull)
#define WS_ACCUM   (WS_SIG + 131072ull)           // float[16]
#define WS_LISTCNT (WS_ACCUM + 256ull)            // int
#define WS_LIST    (WS_LISTCNT + 256ull)          // int4[LIST_CAP]
#define WS_MASK    (WS_LIST + 1048576ull)         // uint[1024*1024]
#define WS_DIAG    (WS_MASK + 4194304ull)         // float[32*1024]

// ---------------- kernel 1: stats + bf16 transpose (single pass) ----------------
// grid (16 wtiles, 32 b), block 256. Each block owns a 64-w strip over all T.
// Also zeros mask/accum/listcnt (used by later kernels in the same stream).
__global__ __launch_bounds__(256) void stats_transpose(
    const float* __restrict__ x, bf16_t* __restrict__ xT,
    float* __restrict__ mu, float* __restrict__ sig,
    unsigned int* __restrict__ mask, float* __restrict__ accum,
    int* __restrict__ listcnt) {
  int b = blockIdx.y, w0 = blockIdx.x * 64;
  int bid = blockIdx.y * 16 + blockIdx.x;     // 0..511
  int tid = threadIdx.x;
  { // fold in the zeroing the old memsets did (1M uints / 512 blocks = 512 uint4)
    uint4* m4 = (uint4*)mask + (size_t)bid * 512;
    uint4 z = {0u, 0u, 0u, 0u};
#pragma unroll
    for (int i = 0; i < 2; ++i) m4[tid + 256 * i] = z;
    if (bid == 0) {
      if (tid < 16) accum[tid] = 0.f;
      if (tid == 16) *listcnt = 0;
    }
  }
  __shared__ float tile[64][65];
  __shared__ float rs[64][17], rq[64][17];
  int wc = tid & 15, tr = tid >> 4;           // wc: float4 col, tr: t row
  float4 s4 = {0.f, 0.f, 0.f, 0.f}, q4 = {0.f, 0.f, 0.f, 0.f};
  const float4* xp = (const float4*)(x + (size_t)b * T_ * W_ + w0);
  int wrc = tid & 7, wv = tid >> 3;           // write-phase coords

  for (int tc = 0; tc < 32; ++tc) {
    int t0 = tc * 64;
    __syncthreads();                          // tile reuse guard
#pragma unroll
    for (int p = 0; p < 4; ++p) {
      int t = tr + 16 * p;
      float4 v = xp[(size_t)(t0 + t) * 256 + wc];
      s4.x += v.x; s4.y += v.y; s4.z += v.z; s4.w += v.w;
      q4.x += v.x * v.x; q4.y += v.y * v.y; q4.z += v.z * v.z; q4.w += v.w * v.w;
      tile[4 * wc + 0][t] = v.x;
      tile[4 * wc + 1][t] = v.y;
      tile[4 * wc + 2][t] = v.z;
      tile[4 * wc + 3][t] = v.w;
    }
    __syncthreads();
#pragma unroll
    for (int p = 0; p < 2; ++p) {
      int w = wv + 32 * p;
      const float* src = &tile[w][wrc * 8];
      bf16x8 o;
#pragma unroll
      for (int k = 0; k < 8; ++k) o[k] = (bf16_t)src[k];
      *(bf16x8*)(xT + ((size_t)b * W_ + w0 + w) * T_ + t0 + wrc * 8) = o;
    }
  }
  rs[4 * wc + 0][tr] = s4.x; rs[4 * wc + 1][tr] = s4.y;
  rs[4 * wc + 2][tr] = s4.z; rs[4 * wc + 3][tr] = s4.w;
  rq[4 * wc + 0][tr] = q4.x; rq[4 * wc + 1][tr] = q4.y;
  rq[4 * wc + 2][tr] = q4.z; rq[4 * wc + 3][tr] = q4.w;
  __syncthreads();
  if (tid < 64) {
    float s = 0.f, q = 0.f;
#pragma unroll
    for (int i = 0; i < 16; ++i) { s += rs[tid][i]; q += rq[tid][i]; }
    float m = s * (1.0f / 2048.0f);
    float var = (q - s * m) * (1.0f / 2047.0f);
    if (var < 0.f) var = 0.f;
    mu[b * W_ + w0 + tid] = m;
    sig[b * W_ + w0 + tid] = sqrtf(var);
  }
}

// ---------------- kernel 2: batched Gram, double-buffered, 1 barrier/iter ----------
// grid 1152 = 8 xcd * 4 sub * 36 tiles; block 256. BK=32, LDS 2x(8+8)KB = 32 KB.
__global__ __launch_bounds__(256) void gram_kernel(
    const bf16_t* __restrict__ xT, const float* __restrict__ mu,
    const float* __restrict__ sig, unsigned int* __restrict__ mask,
    float* __restrict__ diagv, int* __restrict__ listcnt,
    int4* __restrict__ list, float* __restrict__ accum) {
  int id = blockIdx.x;
  int xcd = id & 7;
  int idx = id >> 3;
  int sub = idx / 36;
  int rt  = idx % 36;
  int b = sub * 8 + xcd;
  int r = rt, ti = 0;
  while (r >= 8 - ti) { r -= 8 - ti; ++ti; }
  int tj = ti + r;
  int i0 = ti * 128, j0 = tj * 128;

  const bf16_t* Ag = xT + ((size_t)b * W_ + i0) * T_;
  const bf16_t* Bg = xT + ((size_t)b * W_ + j0) * T_;

  __shared__ __attribute__((aligned(16))) bf16_t As[2][128 * 32];
  __shared__ __attribute__((aligned(16))) bf16_t Bs[2][128 * 32];

  int tid = threadIdx.x;
  int lane = tid & 63, wave = tid >> 6;
  int wm = wave >> 1, wn = wave & 1;

  f32x4 zero = {0.f, 0.f, 0.f, 0.f};
  f32x4 acc[4][4];
#pragma unroll
  for (int mi = 0; mi < 4; ++mi)
#pragma unroll
    for (int nj = 0; nj < 4; ++nj) acc[mi][nj] = zero;

  int arow = wm * 64 + (lane & 15);
  int brow = wn * 64 + (lane & 15);
  int q = lane >> 4;                       // k-quarter (16B chunk)

  // staging thread coords (fixed): 512 chunks of 16B per matrix, 2/thread
  int c0 = tid, c1 = 256 + tid;
  int row0 = c0 >> 2, sl0 = (c0 & 3) ^ (row0 & 3) ^ ((row0 >> 2) & 3);
  int row1 = c1 >> 2, sl1 = (c1 & 3) ^ (row1 & 3) ^ ((row1 >> 2) & 3);

#define STAGE(p, k0)                                                                   \
  do {                                                                                 \
    __builtin_amdgcn_global_load_lds(                                                  \
        (const __attribute__((address_space(1))) void*)(Ag + (size_t)row0 * T_ + (k0) + sl0 * 8), \
        (__attribute__((address_space(3))) void*)(&As[p][c0 * 8]), 16, 0, 0);          \
    __builtin_amdgcn_global_load_lds(                                                  \
        (const __attribute__((address_space(1))) void*)(Bg + (size_t)row0 * T_ + (k0) + sl0 * 8), \
        (__attribute__((address_space(3))) void*)(&Bs[p][c0 * 8]), 16, 0, 0);          \
    __builtin_amdgcn_global_load_lds(                                                  \
        (const __attribute__((address_space(1))) void*)(Ag + (size_t)row1 * T_ + (k0) + sl1 * 8), \
        (__attribute__((address_space(3))) void*)(&As[p][c1 * 8]), 16, 0, 0);          \
    __builtin_amdgcn_global_load_lds(                                                  \
        (const __attribute__((address_space(1))) void*)(Bg + (size_t)row1 * T_ + (k0) + sl1 * 8), \
        (__attribute__((address_space(3))) void*)(&Bs[p][c1 * 8]), 16, 0, 0);          \
  } while (0)

  STAGE(0, 0);
#pragma unroll 2
  for (int it = 0; it < 64; ++it) {
    int p = it & 1;
    __syncthreads();                 // drains stage(it) vmcnt + prior ds_reads
    if (it < 63) STAGE(p ^ 1, (it + 1) * 32);
    bf16x8 af[4], bfr[4];
#pragma unroll
    for (int mi = 0; mi < 4; ++mi) {
      int row = arow + mi * 16;
      af[mi] = *(const bf16x8*)(&As[p][row * 32 + ((q ^ (row & 3) ^ ((row >> 2) & 3)) * 8)]);
    }
#pragma unroll
    for (int nj = 0; nj < 4; ++nj) {
      int row = brow + nj * 16;
      bfr[nj] = *(const bf16x8*)(&Bs[p][row * 32 + ((q ^ (row & 3) ^ ((row >> 2) & 3)) * 8)]);
    }
#pragma unroll
    for (int mi = 0; mi < 4; ++mi)
#pragma unroll
      for (int nj = 0; nj < 4; ++nj)
        acc[mi][nj] = __builtin_amdgcn_mfma_f32_16x16x32_bf16(af[mi], bfr[nj], acc[mi][nj], 0, 0, 0);
  }
#undef STAGE

  // ---- epilogue (unchanged, verified) ----
  const float inv = 1.0f / 2047.0f;
  const float* mub = mu + b * W_;
  const float* sgb = sig + b * W_;
  bool diagquad = (ti == tj) && (wm == wn);
  float gsum = 0.f;

#pragma unroll
  for (int nj = 0; nj < 4; ++nj) {
    int j = j0 + wn * 64 + nj * 16 + (lane & 15);
    float muj = mub[j], sgj = sgb[j];
#pragma unroll
    for (int mi = 0; mi < 4; ++mi) {
#pragma unroll
      for (int rr = 0; rr < 4; ++rr) {
        int i = i0 + wm * 64 + mi * 16 + (lane >> 4) * 4 + rr;
        float cov = (acc[mi][nj][rr] - 2048.0f * mub[i] * muj) * inv;
        float corr = cov / (sgb[i] * sgj + 1e-8f);
        corr = fminf(1.0f, fmaxf(-1.0f, corr));
        if (diagquad && (i != j)) gsum += fabsf(corr);
        if (fabsf(corr) > 0.5f) {
          atomicOr(&mask[i * W_ + j], 1u << b);
          if (i == j) {
            diagv[b * W_ + i] = corr;
          } else {
            int p2 = atomicAdd(listcnt, 1);
            if (p2 < LIST_CAP) list[p2] = make_int4(b, i, j, __float_as_int(corr));
          }
          if (ti != tj) {
            atomicOr(&mask[j * W_ + i], 1u << b);
            int p2 = atomicAdd(listcnt, 1);
            if (p2 < LIST_CAP) list[p2] = make_int4(b, j, i, __float_as_int(corr));
          }
        }
      }
    }
  }
  if (diagquad) {
    for (int o = 32; o > 0; o >>= 1) gsum += __shfl_down(gsum, o);
    if (lane == 0) atomicAdd(&accum[ti * 2 + wm], gsum);
  }
}

// ---------------- kernel 3: EMA scan apply (+ correlations finalize) -------------
__global__ void ema_kernel(const float* __restrict__ ema,
                           const unsigned int* __restrict__ mask,
                           const float* __restrict__ diagv,
                           const int* __restrict__ listcnt,
                           const int4* __restrict__ list,
                           float* __restrict__ emaout,
                           const float* __restrict__ accum,
                           float* __restrict__ outc) {
  if (blockIdx.x == 0 && threadIdx.x < 16)
    outc[threadIdx.x] = accum[threadIdx.x] * (1.0f / (32.0f * 4032.0f));
  int idx = blockIdx.x * 256 + threadIdx.x;   // 1M
  int i = idx >> 10, j = idx & 1023;
  float e = ema[idx];
  unsigned int m = mask[idx];
  if (m) {
    if (i == j) {
      for (int b = 0; b < 32; ++b)
        if ((m >> b) & 1u) e = 0.9f * e + 0.1f * diagv[b * W_ + i];
    } else {
      int cnt = *listcnt; if (cnt > LIST_CAP) cnt = LIST_CAP;
      for (int b = 0; b < 32; ++b) {
        if ((m >> b) & 1u) {
          for (int k = 0; k < cnt; ++k) {
            int4 t = list[k];
            if (t.x == b && t.y == i && t.z == j) {
              e = 0.9f * e + 0.1f * __int_as_float(t.w);
              break;
            }
          }
        }
      }
    }
  }
  emaout[idx] = e;
}

// ---------------- kernel 4: per-group expert MLP (v3) ----------------
// grid 4096 (BT/16), block 256. Lane: dl=tid&3 (16-d chunk), g=(tid>>2)&15,
// tp=tid>>6 (4-t pack). W1 via distinct-address ds_read_b128; reduce via
// __shfl_xor(1,2) (quad DPP). Each thread register-tiles 4 t's.
__global__ void mlp_kernel(
    const float* __restrict__ x, const float* __restrict__ W1,
    const float* __restrict__ b1, const float* __restrict__ W2,
    const float* __restrict__ b2, float* __restrict__ out) {
  __shared__ float4 W1s4[4112];               // 16g*16j*16d4 + pad g
  __shared__ float b1s[256], W2s[256], b2s[16];
  int tid = threadIdx.x;
  const float4* W1f4 = (const float4*)W1;
#pragma unroll
  for (int p = 0; p < 16; ++p) {
    int idx = tid + 256 * p;
    W1s4[idx + (idx >> 8)] = W1f4[idx];
  }
  b1s[tid] = b1[tid];
  W2s[tid] = W2[tid];
  if (tid < 16) b2s[tid] = b2[tid];
  __syncthreads();

  int dl = tid & 3, g = (tid >> 2) & 15, tp = tid >> 6;
  size_t bt0 = (size_t)blockIdx.x * 16 + tp * 4;
  const float4* xf4 = (const float4*)x;

  float4 xv[4][4];
#pragma unroll
  for (int i = 0; i < 4; ++i)
#pragma unroll
    for (int c = 0; c < 4; ++c)
      xv[i][c] = xf4[(bt0 + i) * 256 + g * 16 + dl * 4 + c];

  float ph[4][16];
#pragma unroll
  for (int i = 0; i < 4; ++i)
#pragma unroll
    for (int j = 0; j < 16; ++j) ph[i][j] = 0.f;

  const float4* wbase = &W1s4[g * 257 + dl * 4];
#pragma unroll
  for (int j = 0; j < 16; ++j) {
    float4 w0 = wbase[j * 16 + 0];
    float4 w1 = wbase[j * 16 + 1];
    float4 w2 = wbase[j * 16 + 2];
    float4 w3 = wbase[j * 16 + 3];
#pragma unroll
    for (int i = 0; i < 4; ++i) {
      float a = xv[i][0].x * w0.x + xv[i][0].y * w0.y + xv[i][0].z * w0.z + xv[i][0].w * w0.w;
      a += xv[i][1].x * w1.x + xv[i][1].y * w1.y + xv[i][1].z * w1.z + xv[i][1].w * w1.w;
      a += xv[i][2].x * w2.x + xv[i][2].y * w2.y + xv[i][2].z * w2.z + xv[i][2].w * w2.w;
      a += xv[i][3].x * w3.x + xv[i][3].y * w3.y + xv[i][3].z * w3.z + xv[i][3].w * w3.w;
      ph[i][j] += a;
    }
  }

#pragma unroll
  for (int i = 0; i < 4; ++i) {
    float o = b2s[g];
#pragma unroll
    for (int j = 0; j < 16; ++j) {
      float v = ph[i][j];
      v += __shfl_xor(v, 1);
      v += __shfl_xor(v, 2);
      v += b1s[g * 16 + j];
      o += fmaxf(v, 0.f) * W2s[g * 16 + j];
    }
    if (dl == 0) out[(bt0 + i) * 16 + g] = o;
  }
}

// ---------------- launch ----------------
extern "C" void kernel_launch(void* const* d_in, const int* in_sizes, int n_in,
                              void* d_out, int out_size, void* d_ws, size_t ws_size,
                              hipStream_t stream) {
  const float* x   = (const float*)d_in[0];
  const float* ema = (const float*)d_in[1];
  const float* W1  = (const float*)d_in[2];
  const float* b1  = (const float*)d_in[3];
  const float* W2  = (const float*)d_in[4];
  const float* b2  = (const float*)d_in[5];

  float* out    = (float*)d_out;          // [32][2048][16]
  float* outc   = out + 1048576;          // [16]
  float* outema = outc + 16;              // [1024][1024]

  char* ws = (char*)d_ws;
  bf16_t* xT        = (bf16_t*)(ws + WS_XT);
  float* mub        = (float*)(ws + WS_MU);
  float* sigb       = (float*)(ws + WS_SIG);
  float* accum      = (float*)(ws + WS_ACCUM);
  int*   listcnt    = (int*)(ws + WS_LISTCNT);
  int4*  list       = (int4*)(ws + WS_LIST);
  unsigned int* msk = (unsigned int*)(ws + WS_MASK);
  float* diagv      = (float*)(ws + WS_DIAG);

  stats_transpose<<<dim3(16, 32), 256, 0, stream>>>(x, xT, mub, sigb, msk, accum, listcnt);
  gram_kernel<<<1152, 256, 0, stream>>>(xT, mub, sigb, msk, diagv, listcnt, list, accum);
  ema_kernel<<<4096, 256, 0, stream>>>(ema, msk, diagv, listcnt, list, outema, accum, outc);
  mlp_kernel<<<4096, 256, 0, stream>>>(x, W1, b1, W2, b2, out);
}

// Round 5
// 766.737 us; speedup vs baseline: 1.7759x; 1.7759x over previous
//
#include <hip/hip_runtime.h>
#include <hip/hip_bf16.h>
#include <stdint.h>

// Problem constants
#define B_   32
#define T_   2048
#define W_   1024
#define LIST_CAP 65536

typedef __bf16 bf16_t;
typedef __bf16 bf16x8 __attribute__((ext_vector_type(8)));
typedef float  f32x4  __attribute__((ext_vector_type(4)));

// ---------------- workspace layout (bytes) ----------------
#define WS_XT      0ull
#define WS_XT_SZ   (134217728ull)                 // 32*1024*2048*2
#define WS_MU      (WS_XT + WS_XT_SZ)             // float[32*1024]
#define WS_SIG     (WS_MU  + 131072ull)
#define WS_ACCUM   (WS_SIG + 131072ull)           // float[16]
#define WS_LISTCNT (WS_ACCUM + 256ull)            // int
#define WS_LIST    (WS_LISTCNT + 256ull)          // int4[LIST_CAP]
#define WS_MASK    (WS_LIST + 1048576ull)         // uint[1024*1024]
#define WS_DIAG    (WS_MASK + 4194304ull)         // float[32*1024]

// ---------------- kernel 1: stats + bf16 transpose (single pass) ----------------
__global__ __launch_bounds__(256) void stats_transpose(
    const float* __restrict__ x, bf16_t* __restrict__ xT,
    float* __restrict__ mu, float* __restrict__ sig,
    unsigned int* __restrict__ mask, float* __restrict__ accum,
    int* __restrict__ listcnt) {
  int b = blockIdx.y, w0 = blockIdx.x * 64;
  int bid = blockIdx.y * 16 + blockIdx.x;     // 0..511
  int tid = threadIdx.x;
  { // fold in zeroing of mask/accum/listcnt
    uint4* m4 = (uint4*)mask + (size_t)bid * 512;
    uint4 z = {0u, 0u, 0u, 0u};
#pragma unroll
    for (int i = 0; i < 2; ++i) m4[tid + 256 * i] = z;
    if (bid == 0) {
      if (tid < 16) accum[tid] = 0.f;
      if (tid == 16) *listcnt = 0;
    }
  }
  __shared__ float tile[64][65];
  __shared__ float rs[64][17], rq[64][17];
  int wc = tid & 15, tr = tid >> 4;
  float4 s4 = {0.f, 0.f, 0.f, 0.f}, q4 = {0.f, 0.f, 0.f, 0.f};
  const float4* xp = (const float4*)(x + (size_t)b * T_ * W_ + w0);
  int wrc = tid & 7, wv = tid >> 3;

  for (int tc = 0; tc < 32; ++tc) {
    int t0 = tc * 64;
    __syncthreads();
#pragma unroll
    for (int p = 0; p < 4; ++p) {
      int t = tr + 16 * p;
      float4 v = xp[(size_t)(t0 + t) * 256 + wc];
      s4.x += v.x; s4.y += v.y; s4.z += v.z; s4.w += v.w;
      q4.x += v.x * v.x; q4.y += v.y * v.y; q4.z += v.z * v.z; q4.w += v.w * v.w;
      tile[4 * wc + 0][t] = v.x;
      tile[4 * wc + 1][t] = v.y;
      tile[4 * wc + 2][t] = v.z;
      tile[4 * wc + 3][t] = v.w;
    }
    __syncthreads();
#pragma unroll
    for (int p = 0; p < 2; ++p) {
      int w = wv + 32 * p;
      const float* src = &tile[w][wrc * 8];
      bf16x8 o;
#pragma unroll
      for (int k = 0; k < 8; ++k) o[k] = (bf16_t)src[k];
      *(bf16x8*)(xT + ((size_t)b * W_ + w0 + w) * T_ + t0 + wrc * 8) = o;
    }
  }
  rs[4 * wc + 0][tr] = s4.x; rs[4 * wc + 1][tr] = s4.y;
  rs[4 * wc + 2][tr] = s4.z; rs[4 * wc + 3][tr] = s4.w;
  rq[4 * wc + 0][tr] = q4.x; rq[4 * wc + 1][tr] = q4.y;
  rq[4 * wc + 2][tr] = q4.z; rq[4 * wc + 3][tr] = q4.w;
  __syncthreads();
  if (tid < 64) {
    float s = 0.f, q = 0.f;
#pragma unroll
    for (int i = 0; i < 16; ++i) { s += rs[tid][i]; q += rq[tid][i]; }
    float m = s * (1.0f / 2048.0f);
    float var = (q - s * m) * (1.0f / 2047.0f);
    if (var < 0.f) var = 0.f;
    mu[b * W_ + w0 + tid] = m;
    sig[b * W_ + w0 + tid] = sqrtf(var);
  }
}

// ---------------- kernel 2: batched Gram, double-buffered ----------------
__global__ __launch_bounds__(256) void gram_kernel(
    const bf16_t* __restrict__ xT, const float* __restrict__ mu,
    const float* __restrict__ sig, unsigned int* __restrict__ mask,
    float* __restrict__ diagv, int* __restrict__ listcnt,
    int4* __restrict__ list, float* __restrict__ accum) {
  int id = blockIdx.x;
  int xcd = id & 7;
  int idx = id >> 3;
  int sub = idx / 36;
  int rt  = idx % 36;
  int b = sub * 8 + xcd;
  int r = rt, ti = 0;
  while (r >= 8 - ti) { r -= 8 - ti; ++ti; }
  int tj = ti + r;
  int i0 = ti * 128, j0 = tj * 128;

  const bf16_t* Ag = xT + ((size_t)b * W_ + i0) * T_;
  const bf16_t* Bg = xT + ((size_t)b * W_ + j0) * T_;

  __shared__ __attribute__((aligned(16))) bf16_t As[2][128 * 32];
  __shared__ __attribute__((aligned(16))) bf16_t Bs[2][128 * 32];

  int tid = threadIdx.x;
  int lane = tid & 63, wave = tid >> 6;
  int wm = wave >> 1, wn = wave & 1;

  f32x4 zero = {0.f, 0.f, 0.f, 0.f};
  f32x4 acc[4][4];
#pragma unroll
  for (int mi = 0; mi < 4; ++mi)
#pragma unroll
    for (int nj = 0; nj < 4; ++nj) acc[mi][nj] = zero;

  int arow = wm * 64 + (lane & 15);
  int brow = wn * 64 + (lane & 15);
  int q = lane >> 4;

  int c0 = tid, c1 = 256 + tid;
  int row0 = c0 >> 2, sl0 = (c0 & 3) ^ (row0 & 3) ^ ((row0 >> 2) & 3);
  int row1 = c1 >> 2, sl1 = (c1 & 3) ^ (row1 & 3) ^ ((row1 >> 2) & 3);

#define STAGE(p, k0)                                                                   \
  do {                                                                                 \
    __builtin_amdgcn_global_load_lds(                                                  \
        (const __attribute__((address_space(1))) void*)(Ag + (size_t)row0 * T_ + (k0) + sl0 * 8), \
        (__attribute__((address_space(3))) void*)(&As[p][c0 * 8]), 16, 0, 0);          \
    __builtin_amdgcn_global_load_lds(                                                  \
        (const __attribute__((address_space(1))) void*)(Bg + (size_t)row0 * T_ + (k0) + sl0 * 8), \
        (__attribute__((address_space(3))) void*)(&Bs[p][c0 * 8]), 16, 0, 0);          \
    __builtin_amdgcn_global_load_lds(                                                  \
        (const __attribute__((address_space(1))) void*)(Ag + (size_t)row1 * T_ + (k0) + sl1 * 8), \
        (__attribute__((address_space(3))) void*)(&As[p][c1 * 8]), 16, 0, 0);          \
    __builtin_amdgcn_global_load_lds(                                                  \
        (const __attribute__((address_space(1))) void*)(Bg + (size_t)row1 * T_ + (k0) + sl1 * 8), \
        (__attribute__((address_space(3))) void*)(&Bs[p][c1 * 8]), 16, 0, 0);          \
  } while (0)

  STAGE(0, 0);
#pragma unroll 2
  for (int it = 0; it < 64; ++it) {
    int p = it & 1;
    __syncthreads();
    if (it < 63) STAGE(p ^ 1, (it + 1) * 32);
    bf16x8 af[4], bfr[4];
#pragma unroll
    for (int mi = 0; mi < 4; ++mi) {
      int row = arow + mi * 16;
      af[mi] = *(const bf16x8*)(&As[p][row * 32 + ((q ^ (row & 3) ^ ((row >> 2) & 3)) * 8)]);
    }
#pragma unroll
    for (int nj = 0; nj < 4; ++nj) {
      int row = brow + nj * 16;
      bfr[nj] = *(const bf16x8*)(&Bs[p][row * 32 + ((q ^ (row & 3) ^ ((row >> 2) & 3)) * 8)]);
    }
#pragma unroll
    for (int mi = 0; mi < 4; ++mi)
#pragma unroll
      for (int nj = 0; nj < 4; ++nj)
        acc[mi][nj] = __builtin_amdgcn_mfma_f32_16x16x32_bf16(af[mi], bfr[nj], acc[mi][nj], 0, 0, 0);
  }
#undef STAGE

  const float inv = 1.0f / 2047.0f;
  const float* mub = mu + b * W_;
  const float* sgb = sig + b * W_;
  bool diagquad = (ti == tj) && (wm == wn);
  float gsum = 0.f;

#pragma unroll
  for (int nj = 0; nj < 4; ++nj) {
    int j = j0 + wn * 64 + nj * 16 + (lane & 15);
    float muj = mub[j], sgj = sgb[j];
#pragma unroll
    for (int mi = 0; mi < 4; ++mi) {
#pragma unroll
      for (int rr = 0; rr < 4; ++rr) {
        int i = i0 + wm * 64 + mi * 16 + (lane >> 4) * 4 + rr;
        float cov = (acc[mi][nj][rr] - 2048.0f * mub[i] * muj) * inv;
        float corr = cov / (sgb[i] * sgj + 1e-8f);
        corr = fminf(1.0f, fmaxf(-1.0f, corr));
        if (diagquad && (i != j)) gsum += fabsf(corr);
        if (fabsf(corr) > 0.5f) {
          atomicOr(&mask[i * W_ + j], 1u << b);
          if (i == j) {
            diagv[b * W_ + i] = corr;
          } else {
            int p2 = atomicAdd(listcnt, 1);
            if (p2 < LIST_CAP) list[p2] = make_int4(b, i, j, __float_as_int(corr));
          }
          if (ti != tj) {
            atomicOr(&mask[j * W_ + i], 1u << b);
            int p2 = atomicAdd(listcnt, 1);
            if (p2 < LIST_CAP) list[p2] = make_int4(b, j, i, __float_as_int(corr));
          }
        }
      }
    }
  }
  if (diagquad) {
    for (int o = 32; o > 0; o >>= 1) gsum += __shfl_down(gsum, o);
    if (lane == 0) atomicAdd(&accum[ti * 2 + wm], gsum);
  }
}

// ---------------- kernel 3: EMA scan apply (+ correlations finalize) -------------
__global__ void ema_kernel(const float* __restrict__ ema,
                           const unsigned int* __restrict__ mask,
                           const float* __restrict__ diagv,
                           const int* __restrict__ listcnt,
                           const int4* __restrict__ list,
                           float* __restrict__ emaout,
                           const float* __restrict__ accum,
                           float* __restrict__ outc) {
  if (blockIdx.x == 0 && threadIdx.x < 16)
    outc[threadIdx.x] = accum[threadIdx.x] * (1.0f / (32.0f * 4032.0f));
  int idx = blockIdx.x * 256 + threadIdx.x;   // 1M
  int i = idx >> 10, j = idx & 1023;
  float e = ema[idx];
  unsigned int m = mask[idx];
  if (m) {
    if (i == j) {
      for (int b = 0; b < 32; ++b)
        if ((m >> b) & 1u) e = 0.9f * e + 0.1f * diagv[b * W_ + i];
    } else {
      int cnt = *listcnt; if (cnt > LIST_CAP) cnt = LIST_CAP;
      for (int b = 0; b < 32; ++b) {
        if ((m >> b) & 1u) {
          for (int k = 0; k < cnt; ++k) {
            int4 t = list[k];
            if (t.x == b && t.y == i && t.z == j) {
              e = 0.9f * e + 0.1f * __int_as_float(t.w);
              break;
            }
          }
        }
      }
    }
  }
  emaout[idx] = e;
}

// ---------------- kernel 4: per-group expert MLP (v4: no spills) ----------------
// grid 1024 (BT/64), block 256. Thread = (g = tid&15, 4 consecutive t's).
// Persistent regs: h[4][16]=64 + xv[4]=16 -> ~100 VGPR, budget 128 via
// __launch_bounds__(256,4). W1 in padded LDS (profiled 0 conflicts in R3).
__global__ __launch_bounds__(256, 4) void mlp_kernel(
    const float* __restrict__ x, const float* __restrict__ W1,
    const float* __restrict__ b1, const float* __restrict__ W2,
    const float* __restrict__ b2, float* __restrict__ out) {
  __shared__ float4 W1s4[4112];               // [g][j][d4] + 1 float4 pad per g
  __shared__ float b1s[256], W2s[256], b2s[16];
  int tid = threadIdx.x;
  const float4* W1f4 = (const float4*)W1;
#pragma unroll
  for (int p = 0; p < 16; ++p) {
    int idx = tid + 256 * p;
    W1s4[idx + (idx >> 8)] = W1f4[idx];
  }
  b1s[tid] = b1[tid];
  W2s[tid] = W2[tid];
  if (tid < 16) b2s[tid] = b2[tid];
  __syncthreads();

  int g = tid & 15, tq = tid >> 4;            // tq 0..15
  size_t t0 = (size_t)blockIdx.x * 64 + tq * 4;
  const float4* xf4 = (const float4*)x;       // flat [B*T][256]

  float h[4][16];
#pragma unroll
  for (int i = 0; i < 4; ++i)
#pragma unroll
    for (int j = 0; j < 16; ++j) h[i][j] = 0.f;

  const float4* wbase = &W1s4[g * 257];
#pragma unroll 2
  for (int d4 = 0; d4 < 16; ++d4) {
    float4 xv[4];
#pragma unroll
    for (int i = 0; i < 4; ++i)
      xv[i] = xf4[(t0 + i) * 256 + g * 16 + d4];
#pragma unroll
    for (int j = 0; j < 16; ++j) {
      float4 w = wbase[j * 16 + d4];
#pragma unroll
      for (int i = 0; i < 4; ++i)
        h[i][j] += xv[i].x * w.x + xv[i].y * w.y + xv[i].z * w.z + xv[i].w * w.w;
    }
  }

#pragma unroll
  for (int i = 0; i < 4; ++i) {
    float o = b2s[g];
#pragma unroll
    for (int j = 0; j < 16; ++j)
      o += fmaxf(h[i][j] + b1s[g * 16 + j], 0.f) * W2s[g * 16 + j];
    out[(t0 + i) * 16 + g] = o;
  }
}

// ---------------- launch ----------------
extern "C" void kernel_launch(void* const* d_in, const int* in_sizes, int n_in,
                              void* d_out, int out_size, void* d_ws, size_t ws_size,
                              hipStream_t stream) {
  const float* x   = (const float*)d_in[0];
  const float* ema = (const float*)d_in[1];
  const float* W1  = (const float*)d_in[2];
  const float* b1  = (const float*)d_in[3];
  const float* W2  = (const float*)d_in[4];
  const float* b2  = (const float*)d_in[5];

  float* out    = (float*)d_out;          // [32][2048][16]
  float* outc   = out + 1048576;          // [16]
  float* outema = outc + 16;              // [1024][1024]

  char* ws = (char*)d_ws;
  bf16_t* xT        = (bf16_t*)(ws + WS_XT);
  float* mub        = (float*)(ws + WS_MU);
  float* sigb       = (float*)(ws + WS_SIG);
  float* accum      = (float*)(ws + WS_ACCUM);
  int*   listcnt    = (int*)(ws + WS_LISTCNT);
  int4*  list       = (int4*)(ws + WS_LIST);
  unsigned int* msk = (unsigned int*)(ws + WS_MASK);
  float* diagv      = (float*)(ws + WS_DIAG);

  stats_transpose<<<dim3(16, 32), 256, 0, stream>>>(x, xT, mub, sigb, msk, accum, listcnt);
  gram_kernel<<<1152, 256, 0, stream>>>(xT, mub, sigb, msk, diagv, listcnt, list, accum);
  ema_kernel<<<4096, 256, 0, stream>>>(ema, msk, diagv, listcnt, list, outema, accum, outc);
  mlp_kernel<<<1024, 256, 0, stream>>>(x, W1, b1, W2, b2, out);
}